// Round 3
// baseline (360.459 us; speedup 1.0000x reference)
//
#include <hip/hip_runtime.h>
#include <hip/hip_bf16.h>

typedef __attribute__((ext_vector_type(8))) __bf16 bf16x8;
typedef __attribute__((ext_vector_type(4))) float f32x4;
typedef __attribute__((ext_vector_type(4))) int   i32x4;
typedef unsigned short u16;

// Problem constants: B=2, N=2048, D_MODEL=512, H=8, DK=DV=64
// I/O is float32. Intermediates in ws are bf16.
// ws layout (u16 elements): 8 buffers of 2M elems each = 32 MB total
//   qA qB k1 k2 v1 v2 O1 O2
#define WS_SEG 2097152

static __device__ __forceinline__ u16 f2b(float f) {
  __hip_bfloat16 h = __float2bfloat16(f);  // RNE
  return __builtin_bit_cast(u16, h);
}
static __device__ __forceinline__ i32x4 cvt8(const float* __restrict__ p) {
  float4 a = *(const float4*)p;
  float4 b = *(const float4*)(p + 4);
  union { i32x4 v; u16 u[8]; } r;
  r.u[0]=f2b(a.x); r.u[1]=f2b(a.y); r.u[2]=f2b(a.z); r.u[3]=f2b(a.w);
  r.u[4]=f2b(b.x); r.u[5]=f2b(b.y); r.u[6]=f2b(b.z); r.u[7]=f2b(b.w);
  return r.v;
}

// ---------------------------------------------------------------------------
// Generic bt-GEMM, 128x128 tile, BK=32, 4 waves each computing 64x64.
// phase 0, z=0..5: projections (writes [b,h,n,d] bf16 into ws)
//   z0: qA = interests@Wq^T + grids@Wq12^T + (bq+bq12)      (K=1024 concat)
//   z1: qB = interests@Wq^T + regions@Wq12^T + (bq+bq12)
//   z2: k1 = (regions@Wk^T + bk) * scale * aw[b,n]
//   z3: k2 = (grids@Wk^T + bk) * scale * aw[b,n]
//   z4: v1 = regions@Wv^T + bv
//   z5: v2 = grids@Wv^T + bv
// phase 1, z=0..1: out_z = O_z @ Wo_z^T + bo_z  -> d_out (f32, [b,n,512])
// ---------------------------------------------------------------------------
__global__ __launch_bounds__(256, 2) void gemm_all(
    const float* __restrict__ regions, const float* __restrict__ grids,
    const float* __restrict__ interests, const float* __restrict__ aw,
    const float* __restrict__ Wq,  const float* __restrict__ bq,
    const float* __restrict__ Wk,  const float* __restrict__ bk,
    const float* __restrict__ Wv,  const float* __restrict__ bv,
    const float* __restrict__ Wq12,const float* __restrict__ bq12,
    const float* __restrict__ Wo1, const float* __restrict__ bo1,
    const float* __restrict__ Wo2, const float* __restrict__ bo2,
    u16* __restrict__ ws, float* __restrict__ out, int phase)
{
  __shared__ u16 As[128 * 40];   // stride 40 (80B, 16B-aligned rows, de-banked)
  __shared__ u16 Bs[128 * 40];

  u16* qA = ws + 0 * WS_SEG;
  u16* qB = ws + 1 * WS_SEG;
  u16* k1 = ws + 2 * WS_SEG;
  u16* k2 = ws + 3 * WS_SEG;
  u16* v1 = ws + 4 * WS_SEG;
  u16* v2 = ws + 5 * WS_SEG;
  u16* O1 = ws + 6 * WS_SEG;
  u16* O2 = ws + 7 * WS_SEG;

  const float *A1 = nullptr, *A2 = nullptr, *Bm1 = nullptr, *Bm2 = nullptr;
  const float *bias1 = nullptr, *bias2 = nullptr;
  const u16* Abf = nullptr;      // phase-1 A (bf16 in ws)
  u16* dst16 = nullptr;
  float* dst32 = nullptr;
  int KT = 512, epi = 0;
  const int z = blockIdx.z;
  if (phase == 0) {
    if (z == 0)      { A1=interests; A2=grids;   Bm1=Wq; Bm2=Wq12; KT=1024; bias1=bq; bias2=bq12; epi=0; dst16=qA; }
    else if (z == 1) { A1=interests; A2=regions; Bm1=Wq; Bm2=Wq12; KT=1024; bias1=bq; bias2=bq12; epi=0; dst16=qB; }
    else if (z == 2) { A1=regions;   Bm1=Wk; bias1=bk; epi=1; dst16=k1; }
    else if (z == 3) { A1=grids;     Bm1=Wk; bias1=bk; epi=1; dst16=k2; }
    else if (z == 4) { A1=regions;   Bm1=Wv; bias1=bv; epi=0; dst16=v1; }
    else             { A1=grids;     Bm1=Wv; bias1=bv; epi=0; dst16=v2; }
  } else {
    if (z == 0) { Abf=O1; Bm1=Wo1; bias1=bo1; epi=2; dst32=out; }
    else        { Abf=O2; Bm1=Wo2; bias1=bo2; epi=2; dst32=out + 2097152; }
  }

  const int t = threadIdx.x;
  const int lane = t & 63, w = t >> 6;
  const int l15 = lane & 15, q4 = lane >> 4;
  const int m0 = blockIdx.y * 128, j0 = blockIdx.x * 128;
  const int ro = (w >> 1) * 64, co = (w & 1) * 64;

  f32x4 acc[4][4];
  for (int i = 0; i < 4; i++)
    for (int j = 0; j < 4; j++) acc[i][j] = (f32x4){0.f, 0.f, 0.f, 0.f};

  for (int k0 = 0; k0 < KT; k0 += 32) {
    const float* Af = A1; const float* Bf = Bm1; int kk = k0;
    if (kk >= 512) { Af = A2; Bf = Bm2; kk -= 512; }   // concat-K second half
    __syncthreads();
    // stage 128x32 tiles: 512 16B-chunks per buffer, 2 chunks/thread
#pragma unroll
    for (int i = 0; i < 2; i++) {
      const int c = t + i * 256;
      const int row = c >> 2, col = (c & 3) * 8;
      if (phase == 0) {
        *(i32x4*)&As[row * 40 + col] = cvt8(&Af[(m0 + row) * 512 + kk + col]);
      } else {
        *(i32x4*)&As[row * 40 + col] = *(const i32x4*)&Abf[(m0 + row) * 512 + kk + col];
      }
      *(i32x4*)&Bs[row * 40 + col] = cvt8(&Bf[(j0 + row) * 512 + kk + col]);
    }
    __syncthreads();
    bf16x8 af[4], bfr[4];
#pragma unroll
    for (int i = 0; i < 4; i++) af[i]  = *(const bf16x8*)&As[(ro + i * 16 + l15) * 40 + q4 * 8];
#pragma unroll
    for (int i = 0; i < 4; i++) bfr[i] = *(const bf16x8*)&Bs[(co + i * 16 + l15) * 40 + q4 * 8];
#pragma unroll
    for (int mt = 0; mt < 4; mt++)
#pragma unroll
      for (int nt = 0; nt < 4; nt++)
        acc[mt][nt] = __builtin_amdgcn_mfma_f32_16x16x32_bf16(af[mt], bfr[nt], acc[mt][nt], 0, 0, 0);
  }

  // epilogue: C row m = m0+ro+mt*16+q4*4+r, col j = j0+co+nt*16+l15
#pragma unroll
  for (int nt = 0; nt < 4; nt++) {
    const int j = j0 + co + nt * 16 + l15;
    float bsum = bias1[j];
    if (bias2) bsum += bias2[j];
#pragma unroll
    for (int mt = 0; mt < 4; mt++) {
#pragma unroll
      for (int r = 0; r < 4; r++) {
        const int m = m0 + ro + mt * 16 + q4 * 4 + r;
        float v = acc[mt][nt][r] + bsum;
        if (epi == 2) {
          dst32[m * 512 + j] = v;
        } else {
          const int b = m >> 11, nn = m & 2047, h = j >> 6, d = j & 63;
          if (epi == 1) v *= 0.125f * aw[b * 2048 + nn];  // scale*aw folded into K
          dst16[((b * 8 + h) * 2048 + nn) * 64 + d] = f2b(v);
        }
      }
    }
  }
}

// ---------------------------------------------------------------------------
// Flash attention: one block = 64 q-rows of one (path, b, h); 4 waves x 16 rows.
// K loop over 32 tiles of 64 keys. scale*aw already folded into K; mask -> -1e30.
// Writes O in [b*2048+q, h*64+d] layout (bf16) ready for the output GEMM.
// ---------------------------------------------------------------------------
__global__ __launch_bounds__(256, 2) void attn_kernel(
    const int* __restrict__ mask_r, const int* __restrict__ mask_g,
    u16* __restrict__ ws)
{
  u16* qA = ws + 0 * WS_SEG;
  u16* qB = ws + 1 * WS_SEG;
  u16* k1 = ws + 2 * WS_SEG;
  u16* k2 = ws + 3 * WS_SEG;
  u16* v1 = ws + 4 * WS_SEG;
  u16* v2 = ws + 5 * WS_SEG;
  u16* O1 = ws + 6 * WS_SEG;
  u16* O2 = ws + 7 * WS_SEG;

  const int qt = blockIdx.x, bh = blockIdx.y, path = blockIdx.z;
  const int b = bh >> 3, h = bh & 7;
  const u16* Q = (path ? qB : qA) + bh * (2048 * 64);
  const u16* K = (path ? k2 : k1) + bh * (2048 * 64);
  const u16* V = (path ? v2 : v1) + bh * (2048 * 64);
  const int* mask = (path ? mask_g : mask_r) + b * 2048;
  u16* O = (path ? O2 : O1) + (b * 2048 + qt * 64) * 512 + h * 64;

  __shared__ u16 Ks[64 * 72];       // [key][d], stride 72
  __shared__ u16 Vt[64 * 72];       // [d][key], stride 72 (transposed at staging)
  __shared__ u16 Ps[4 * 16 * 72];   // per-wave P round-trip, stride 72

  const int t = threadIdx.x, lane = t & 63, w = t >> 6;
  const int l15 = lane & 15, q4 = lane >> 4;

  // Q fragments held in registers for all 32 key-tiles
  bf16x8 qf[2];
  {
    const int qrow = qt * 64 + w * 16 + l15;
    qf[0] = *(const bf16x8*)&Q[qrow * 64 + q4 * 8];
    qf[1] = *(const bf16x8*)&Q[qrow * 64 + 32 + q4 * 8];
  }

  float m_run[4], l_run[4];
  f32x4 o_acc[4];
  for (int r = 0; r < 4; r++) { m_run[r] = -1e30f; l_run[r] = 0.f; }
  for (int d = 0; d < 4; d++) o_acc[d] = (f32x4){0.f, 0.f, 0.f, 0.f};

  for (int kt = 0; kt < 32; kt++) {
    __syncthreads();
#pragma unroll
    for (int seg = 0; seg < 2; seg++) {           // stage 64x64 K and V^T
      const int e = seg * 2048 + t * 8;
      const int row = e >> 6, col = e & 63;
      i32x4 kv = *(const i32x4*)&K[kt * 4096 + e];
      *(i32x4*)&Ks[row * 72 + col] = kv;
      i32x4 vv = *(const i32x4*)&V[kt * 4096 + e];
      union { i32x4 v4; u16 u[8]; } uv; uv.v4 = vv;
#pragma unroll
      for (int i = 0; i < 8; i++) Vt[(col + i) * 72 + row] = uv.u[i];
    }
    __syncthreads();

    // S = Q K^T  (scale & aw pre-folded into K)
    f32x4 s[4];
#pragma unroll
    for (int nt = 0; nt < 4; nt++) {
      s[nt] = (f32x4){0.f, 0.f, 0.f, 0.f};
#pragma unroll
      for (int ss = 0; ss < 2; ss++) {
        bf16x8 kf = *(const bf16x8*)&Ks[(nt * 16 + l15) * 72 + ss * 32 + q4 * 8];
        s[nt] = __builtin_amdgcn_mfma_f32_16x16x32_bf16(qf[ss], kf, s[nt], 0, 0, 0);
      }
    }
    // mask (col = lane&15 for all 4 regs)
#pragma unroll
    for (int nt = 0; nt < 4; nt++) {
      const int kg = kt * 64 + nt * 16 + l15;
      if (mask[kg]) s[nt] = (f32x4){-1e30f, -1e30f, -1e30f, -1e30f};
    }
    // online softmax: rows live at (q4*4+r), cols across lane&15
    float mx[4];
#pragma unroll
    for (int r = 0; r < 4; r++)
      mx[r] = fmaxf(fmaxf(s[0][r], s[1][r]), fmaxf(s[2][r], s[3][r]));
#pragma unroll
    for (int d = 1; d < 16; d <<= 1)
#pragma unroll
      for (int r = 0; r < 4; r++) mx[r] = fmaxf(mx[r], __shfl_xor(mx[r], d));
    float alpha[4], lsum[4];
#pragma unroll
    for (int r = 0; r < 4; r++) {
      const float mn = fmaxf(m_run[r], mx[r]);
      alpha[r] = __expf(m_run[r] - mn);
      m_run[r] = mn;
      lsum[r] = 0.f;
    }
#pragma unroll
    for (int nt = 0; nt < 4; nt++)
#pragma unroll
      for (int r = 0; r < 4; r++) {
        const float p = __expf(s[nt][r] - m_run[r]);
        s[nt][r] = p;
        lsum[r] += p;
      }
#pragma unroll
    for (int d = 1; d < 16; d <<= 1)
#pragma unroll
      for (int r = 0; r < 4; r++) lsum[r] += __shfl_xor(lsum[r], d);
#pragma unroll
    for (int r = 0; r < 4; r++) l_run[r] = l_run[r] * alpha[r] + lsum[r];
#pragma unroll
    for (int dt = 0; dt < 4; dt++)
#pragma unroll
      for (int r = 0; r < 4; r++) o_acc[dt][r] *= alpha[r];

    // P: C-layout -> A-layout via per-wave LDS round trip
#pragma unroll
    for (int nt = 0; nt < 4; nt++)
#pragma unroll
      for (int r = 0; r < 4; r++)
        Ps[(w * 16 + q4 * 4 + r) * 72 + nt * 16 + l15] = f2b(s[nt][r]);
    asm volatile("s_waitcnt lgkmcnt(0)" ::: "memory");  // wave-local RAW on Ps

    // O += P V
#pragma unroll
    for (int ss = 0; ss < 2; ss++) {
      bf16x8 pf = *(const bf16x8*)&Ps[(w * 16 + l15) * 72 + ss * 32 + q4 * 8];
#pragma unroll
      for (int dt = 0; dt < 4; dt++) {
        bf16x8 vf = *(const bf16x8*)&Vt[(dt * 16 + l15) * 72 + ss * 32 + q4 * 8];
        o_acc[dt] = __builtin_amdgcn_mfma_f32_16x16x32_bf16(pf, vf, o_acc[dt], 0, 0, 0);
      }
    }
  }

  // O /= l, write [q, h*64+d]
#pragma unroll
  for (int dt = 0; dt < 4; dt++)
#pragma unroll
    for (int r = 0; r < 4; r++) {
      const float v = o_acc[dt][r] / l_run[r];
      O[(w * 16 + q4 * 4 + r) * 512 + dt * 16 + l15] = f2b(v);
    }
}

extern "C" void kernel_launch(void* const* d_in, const int* in_sizes, int n_in,
                              void* d_out, int out_size, void* d_ws, size_t ws_size,
                              hipStream_t stream) {
  const float* regions   = (const float*)d_in[0];
  const float* grids     = (const float*)d_in[1];
  const float* interests = (const float*)d_in[2];
  const int*   mask_r    = (const int*)d_in[3];
  const int*   mask_g    = (const int*)d_in[4];
  const float* aw        = (const float*)d_in[5];
  const float* Wq  = (const float*)d_in[6];  const float* bq  = (const float*)d_in[7];
  const float* Wk  = (const float*)d_in[8];  const float* bk  = (const float*)d_in[9];
  const float* Wv  = (const float*)d_in[10]; const float* bv  = (const float*)d_in[11];
  const float* Wq12= (const float*)d_in[12]; const float* bq12= (const float*)d_in[13];
  const float* Wo1 = (const float*)d_in[14]; const float* bo1 = (const float*)d_in[15];
  const float* Wo2 = (const float*)d_in[16]; const float* bo2 = (const float*)d_in[17];
  u16*   ws  = (u16*)d_ws;
  float* out = (float*)d_out;

  // 1) projections: qA,qB (K=1024 folded sums), k1,k2 (scale*aw folded), v1,v2
  gemm_all<<<dim3(4, 32, 6), 256, 0, stream>>>(regions, grids, interests, aw,
      Wq, bq, Wk, bk, Wv, bv, Wq12, bq12, Wo1, bo1, Wo2, bo2, ws, out, 0);
  // 2) flash attention, both paths
  attn_kernel<<<dim3(32, 16, 2), 256, 0, stream>>>(mask_r, mask_g, ws);
  // 3) output projections -> d_out (f32)
  gemm_all<<<dim3(4, 32, 2), 256, 0, stream>>>(regions, grids, interests, aw,
      Wq, bq, Wk, bk, Wv, bv, Wq12, bq12, Wo1, bo1, Wo2, bo2, ws, out, 1);
}

// Round 4
// 295.921 us; speedup vs baseline: 1.2181x; 1.2181x over previous
//
#include <hip/hip_runtime.h>
#include <hip/hip_bf16.h>

typedef __attribute__((ext_vector_type(8))) __bf16 bf16x8;
typedef __attribute__((ext_vector_type(4))) float f32x4;
typedef __attribute__((ext_vector_type(4))) int   i32x4;
typedef unsigned short u16;

// B=2, N=2048, D_MODEL=512, H=8, DK=DV=64. I/O f32; ws intermediates bf16.
// ws (u16): qA qB k1 k2 v1 v2 O1 O2, 2M elems each.
// v1/v2 hold V^T: [(b*512 + h*64 + d)][token 2048]
#define WS_SEG 2097152

static __device__ __forceinline__ u16 f2b(float f) {
  __hip_bfloat16 h = __float2bfloat16(f);  // RNE
  return __builtin_bit_cast(u16, h);
}
static __device__ __forceinline__ i32x4 cvt8(const float* __restrict__ p) {
  float4 a = *(const float4*)p;
  float4 b = *(const float4*)(p + 4);
  union { i32x4 v; u16 u[8]; } r;
  r.u[0]=f2b(a.x); r.u[1]=f2b(a.y); r.u[2]=f2b(a.z); r.u[3]=f2b(a.w);
  r.u[4]=f2b(b.x); r.u[5]=f2b(b.y); r.u[6]=f2b(b.z); r.u[7]=f2b(b.w);
  return r.v;
}
static __device__ __forceinline__ float fexp2(float x) {
  float r; asm("v_exp_f32 %0, %1" : "=v"(r) : "v"(x)); return r;
}
template<int C>
static __device__ __forceinline__ float dppf(float x) {
  int v = __builtin_amdgcn_update_dpp(__builtin_bit_cast(int, x),
                                      __builtin_bit_cast(int, x), C, 0xF, 0xF, false);
  return __builtin_bit_cast(float, v);
}
// reduce across the 16 lanes of a DPP row (our l15 group)
static __device__ __forceinline__ float rowmax16(float x) {
  x = fmaxf(x, dppf<0xB1>(x));   // quad_perm(1,0,3,2)  = xor1
  x = fmaxf(x, dppf<0x4E>(x));   // quad_perm(2,3,0,1)  = xor2
  x = fmaxf(x, dppf<0x141>(x));  // row_half_mirror     (crosses 4-boundary)
  x = fmaxf(x, dppf<0x140>(x));  // row_mirror          (crosses 8-boundary)
  return x;
}
static __device__ __forceinline__ float rowsum16(float x) {
  x += dppf<0xB1>(x);
  x += dppf<0x4E>(x);
  x += dppf<0x141>(x);
  x += dppf<0x140>(x);
  return x;
}

// ---------------------------------------------------------------------------
// bt-GEMM, 128x128 tile, BK=32, 4 waves x 64x64.
// phase 0: z0 qA (K=1024 concat), z1 qB, z2 k1 (*scale*aw*log2e), z3 k2,
//          z4 v1^T (swapped operands: C^T = Wv·X^T), z5 v2^T
// phase 1: z0/z1 out = O_z @ Wo_z^T + bo_z -> f32 d_out
// ---------------------------------------------------------------------------
__global__ __launch_bounds__(256, 2) void gemm_all(
    const float* __restrict__ regions, const float* __restrict__ grids,
    const float* __restrict__ interests, const float* __restrict__ aw,
    const float* __restrict__ Wq,  const float* __restrict__ bq,
    const float* __restrict__ Wk,  const float* __restrict__ bk,
    const float* __restrict__ Wv,  const float* __restrict__ bv,
    const float* __restrict__ Wq12,const float* __restrict__ bq12,
    const float* __restrict__ Wo1, const float* __restrict__ bo1,
    const float* __restrict__ Wo2, const float* __restrict__ bo2,
    u16* __restrict__ ws, float* __restrict__ out, int phase)
{
  __shared__ u16 As[128 * 40];
  __shared__ u16 Bs[128 * 40];

  u16* qA = ws + 0 * WS_SEG;
  u16* qB = ws + 1 * WS_SEG;
  u16* k1 = ws + 2 * WS_SEG;
  u16* k2 = ws + 3 * WS_SEG;
  u16* v1 = ws + 4 * WS_SEG;
  u16* v2 = ws + 5 * WS_SEG;
  u16* O1 = ws + 6 * WS_SEG;
  u16* O2 = ws + 7 * WS_SEG;

  const float *A1 = nullptr, *A2 = nullptr, *Bm1 = nullptr, *Bm2 = nullptr;
  const float *bias1 = nullptr, *bias2 = nullptr;
  const u16* Abf = nullptr;
  u16* dst16 = nullptr;
  float* dst32 = nullptr;
  int KT = 512, epi = 0;
  const int z = blockIdx.z;
  if (phase == 0) {
    if (z == 0)      { A1=interests; A2=grids;   Bm1=Wq; Bm2=Wq12; KT=1024; bias1=bq; bias2=bq12; epi=0; dst16=qA; }
    else if (z == 1) { A1=interests; A2=regions; Bm1=Wq; Bm2=Wq12; KT=1024; bias1=bq; bias2=bq12; epi=0; dst16=qB; }
    else if (z == 2) { A1=regions;   Bm1=Wk; bias1=bk; epi=1; dst16=k1; }
    else if (z == 3) { A1=grids;     Bm1=Wk; bias1=bk; epi=1; dst16=k2; }
    else if (z == 4) { A1=regions;   Bm1=Wv; bias1=bv; epi=3; dst16=v1; }  // swapped
    else             { A1=grids;     Bm1=Wv; bias1=bv; epi=3; dst16=v2; }  // swapped
  } else {
    if (z == 0) { Abf=O1; Bm1=Wo1; bias1=bo1; epi=2; dst32=out; }
    else        { Abf=O2; Bm1=Wo2; bias1=bo2; epi=2; dst32=out + 2097152; }
  }
  const bool swp = (epi == 3);

  const int t = threadIdx.x;
  const int lane = t & 63, w = t >> 6;
  const int l15 = lane & 15, q4 = lane >> 4;
  const int m0 = blockIdx.y * 128, j0 = blockIdx.x * 128;
  const int ro = (w >> 1) * 64, co = (w & 1) * 64;

  f32x4 acc[4][4];
  for (int i = 0; i < 4; i++)
    for (int j = 0; j < 4; j++) acc[i][j] = (f32x4){0.f, 0.f, 0.f, 0.f};

  for (int k0 = 0; k0 < KT; k0 += 32) {
    const float* pa; const float* pb; int kk = k0, ra, rb;
    if (swp)            { pa = Bm1; pb = A1;  ra = j0; rb = m0; }
    else if (kk < 512)  { pa = A1;  pb = Bm1; ra = m0; rb = j0; }
    else                { pa = A2;  pb = Bm2; ra = m0; rb = j0; kk -= 512; }
    __syncthreads();
#pragma unroll
    for (int i = 0; i < 2; i++) {
      const int c = t + i * 256;
      const int row = c >> 2, col = (c & 3) * 8;
      if (phase == 0) {
        *(i32x4*)&As[row * 40 + col] = cvt8(&pa[(ra + row) * 512 + kk + col]);
      } else {
        *(i32x4*)&As[row * 40 + col] = *(const i32x4*)&Abf[(m0 + row) * 512 + kk + col];
      }
      *(i32x4*)&Bs[row * 40 + col] = cvt8(&pb[(rb + row) * 512 + kk + col]);
    }
    __syncthreads();
    bf16x8 af[4], bfr[4];
#pragma unroll
    for (int i = 0; i < 4; i++) af[i]  = *(const bf16x8*)&As[(ro + i * 16 + l15) * 40 + q4 * 8];
#pragma unroll
    for (int i = 0; i < 4; i++) bfr[i] = *(const bf16x8*)&Bs[(co + i * 16 + l15) * 40 + q4 * 8];
#pragma unroll
    for (int mt = 0; mt < 4; mt++)
#pragma unroll
      for (int nt = 0; nt < 4; nt++)
        acc[mt][nt] = __builtin_amdgcn_mfma_f32_16x16x32_bf16(af[mt], bfr[nt], acc[mt][nt], 0, 0, 0);
  }

#pragma unroll
  for (int nt = 0; nt < 4; nt++) {
    const int j = j0 + co + nt * 16 + l15;
    if (epi == 3) {
      // swapped: C row = hd (0..511), col = token; write V^T + bias over rows
      const int token = m0 + co + nt * 16 + l15;
      const int bb = token >> 11, nn = token & 2047;
#pragma unroll
      for (int mt = 0; mt < 4; mt++) {
#pragma unroll
        for (int r = 0; r < 4; r++) {
          const int hd = j0 + ro + mt * 16 + q4 * 4 + r;
          const float v = acc[mt][nt][r] + bias1[hd];
          dst16[(bb * 512 + hd) * 2048 + nn] = f2b(v);
        }
      }
    } else {
      float bsum = bias1[j];
      if (bias2) bsum += bias2[j];
#pragma unroll
      for (int mt = 0; mt < 4; mt++) {
#pragma unroll
        for (int r = 0; r < 4; r++) {
          const int m = m0 + ro + mt * 16 + q4 * 4 + r;
          float v = acc[mt][nt][r] + bsum;
          if (epi == 2) {
            dst32[m * 512 + j] = v;
          } else {
            const int b = m >> 11, nn = m & 2047, h = j >> 6, d = j & 63;
            if (epi == 1) v *= 0.18033688f * aw[b * 2048 + nn];  // scale*log2e*aw
            dst16[((b * 8 + h) * 2048 + nn) * 64 + d] = f2b(v);
          }
        }
      }
    }
  }
}

// ---------------------------------------------------------------------------
// Flash attention: block = 128 q-rows of one (path,b,h); wave = 32 rows.
// K pre-scaled by scale*aw*log2e -> softmax in exp2 domain. Mask bias in LDS.
// V^T staged with b128 writes (no transpose). P round-trip XOR-swizzled.
// ---------------------------------------------------------------------------
__global__ __launch_bounds__(256, 2) void attn_kernel(
    const int* __restrict__ mask_r, const int* __restrict__ mask_g,
    u16* __restrict__ ws)
{
  u16* qA = ws + 0 * WS_SEG;
  u16* qB = ws + 1 * WS_SEG;
  u16* k1 = ws + 2 * WS_SEG;
  u16* k2 = ws + 3 * WS_SEG;
  u16* v1 = ws + 4 * WS_SEG;
  u16* v2 = ws + 5 * WS_SEG;
  u16* O1 = ws + 6 * WS_SEG;
  u16* O2 = ws + 7 * WS_SEG;

  const int qt = blockIdx.x, bh = blockIdx.y, path = blockIdx.z;
  const int b = bh >> 3, h = bh & 7;
  const u16* Q  = (path ? qB : qA) + bh * (2048 * 64);
  const u16* K  = (path ? k2 : k1) + bh * (2048 * 64);
  const u16* Vg = (path ? v2 : v1) + (b * 512 + h * 64) * 2048;  // V^T rows
  const int* mask = (path ? mask_g : mask_r) + b * 2048;
  u16* O = (path ? O2 : O1) + (b * 2048 + qt * 128) * 512 + h * 64;

  __shared__ u16 Ks[64 * 72];     // [key][d]
  __shared__ u16 Vs[64 * 72];     // [d][key] (already transposed in ws)
  __shared__ u16 Ps[128 * 64];    // XOR-swizzled P round-trip
  __shared__ float Ms[2048];      // additive mask bias

  const int t = threadIdx.x, lane = t & 63, w = t >> 6;
  const int l15 = lane & 15, q4 = lane >> 4;

  {
    const int4 a = *(const int4*)&mask[t * 8];
    const int4 c = *(const int4*)&mask[t * 8 + 4];
    float4 f1, f2v;
    f1.x = a.x ? -1e30f : 0.f; f1.y = a.y ? -1e30f : 0.f;
    f1.z = a.z ? -1e30f : 0.f; f1.w = a.w ? -1e30f : 0.f;
    f2v.x = c.x ? -1e30f : 0.f; f2v.y = c.y ? -1e30f : 0.f;
    f2v.z = c.z ? -1e30f : 0.f; f2v.w = c.w ? -1e30f : 0.f;
    *(float4*)&Ms[t * 8] = f1;
    *(float4*)&Ms[t * 8 + 4] = f2v;
  }

  bf16x8 qf[2][2];
#pragma unroll
  for (int mt = 0; mt < 2; mt++) {
    const int qrow = qt * 128 + w * 32 + mt * 16 + l15;
    qf[mt][0] = *(const bf16x8*)&Q[qrow * 64 + q4 * 8];
    qf[mt][1] = *(const bf16x8*)&Q[qrow * 64 + 32 + q4 * 8];
  }

  float m_run[2][4], l_run[2][4];
  f32x4 o_acc[2][4];
#pragma unroll
  for (int mt = 0; mt < 2; mt++)
#pragma unroll
    for (int r = 0; r < 4; r++) { m_run[mt][r] = -1e30f; l_run[mt][r] = 0.f; }
#pragma unroll
  for (int mt = 0; mt < 2; mt++)
#pragma unroll
    for (int d = 0; d < 4; d++) o_acc[mt][d] = (f32x4){0.f, 0.f, 0.f, 0.f};

  for (int kt = 0; kt < 32; kt++) {
    __syncthreads();
#pragma unroll
    for (int seg = 0; seg < 2; seg++) {
      const int c = t + seg * 256;
      const int row = c >> 3, col = (c & 7) * 8;
      *(i32x4*)&Ks[row * 72 + col] = *(const i32x4*)&K[(kt * 64 + row) * 64 + col];
      *(i32x4*)&Vs[row * 72 + col] = *(const i32x4*)&Vg[row * 2048 + kt * 64 + col];
    }
    __syncthreads();

    // S = Q K^T (log2-domain: scale*aw*log2e folded into K)
    f32x4 s[2][4];
#pragma unroll
    for (int mt = 0; mt < 2; mt++)
#pragma unroll
      for (int nt = 0; nt < 4; nt++) s[mt][nt] = (f32x4){0.f, 0.f, 0.f, 0.f};
#pragma unroll
    for (int nt = 0; nt < 4; nt++)
#pragma unroll
      for (int ss = 0; ss < 2; ss++) {
        bf16x8 kf = *(const bf16x8*)&Ks[(nt * 16 + l15) * 72 + ss * 32 + q4 * 8];
        s[0][nt] = __builtin_amdgcn_mfma_f32_16x16x32_bf16(qf[0][ss], kf, s[0][nt], 0, 0, 0);
        s[1][nt] = __builtin_amdgcn_mfma_f32_16x16x32_bf16(qf[1][ss], kf, s[1][nt], 0, 0, 0);
      }
    // additive mask bias (per key column)
#pragma unroll
    for (int nt = 0; nt < 4; nt++) {
      const float bias = Ms[kt * 64 + nt * 16 + l15];
      const f32x4 bv4 = (f32x4){bias, bias, bias, bias};
      s[0][nt] += bv4; s[1][nt] += bv4;
    }
    // online softmax (exp2 domain); DPP reductions across the 16 key-columns
#pragma unroll
    for (int mt = 0; mt < 2; mt++) {
#pragma unroll
      for (int r = 0; r < 4; r++) {
        float mx = fmaxf(fmaxf(s[mt][0][r], s[mt][1][r]), fmaxf(s[mt][2][r], s[mt][3][r]));
        mx = rowmax16(mx);
        const float mn = fmaxf(m_run[mt][r], mx);
        const float alpha = fexp2(m_run[mt][r] - mn);
        m_run[mt][r] = mn;
        float ls = 0.f;
#pragma unroll
        for (int nt = 0; nt < 4; nt++) {
          const float p = fexp2(s[mt][nt][r] - mn);
          s[mt][nt][r] = p;
          ls += p;
        }
        ls = rowsum16(ls);
        l_run[mt][r] = l_run[mt][r] * alpha + ls;
#pragma unroll
        for (int dt = 0; dt < 4; dt++) o_acc[mt][dt][r] *= alpha;
      }
    }
    // P: C-layout -> A-layout via XOR-swizzled per-wave LDS round trip
#pragma unroll
    for (int mt = 0; mt < 2; mt++)
#pragma unroll
      for (int nt = 0; nt < 4; nt++) {
        const int cg = 2 * nt + (l15 >> 3);
#pragma unroll
        for (int r = 0; r < 4; r++) {
          const int row = w * 32 + mt * 16 + q4 * 4 + r;
          Ps[row * 64 + ((cg ^ (row & 7)) * 8) + (l15 & 7)] = f2b(s[mt][nt][r]);
        }
      }
    asm volatile("s_waitcnt lgkmcnt(0)" ::: "memory");  // wave-local RAW on Ps

    // O += P V
#pragma unroll
    for (int ss = 0; ss < 2; ss++) {
      bf16x8 pf[2];
#pragma unroll
      for (int mt = 0; mt < 2; mt++) {
        const int row = w * 32 + mt * 16 + l15;
        const int cg = (4 * ss + q4) ^ (row & 7);
        pf[mt] = *(const bf16x8*)&Ps[row * 64 + cg * 8];
      }
#pragma unroll
      for (int dt = 0; dt < 4; dt++) {
        bf16x8 vf = *(const bf16x8*)&Vs[(dt * 16 + l15) * 72 + ss * 32 + q4 * 8];
        o_acc[0][dt] = __builtin_amdgcn_mfma_f32_16x16x32_bf16(pf[0], vf, o_acc[0][dt], 0, 0, 0);
        o_acc[1][dt] = __builtin_amdgcn_mfma_f32_16x16x32_bf16(pf[1], vf, o_acc[1][dt], 0, 0, 0);
      }
    }
  }

#pragma unroll
  for (int mt = 0; mt < 2; mt++)
#pragma unroll
    for (int dt = 0; dt < 4; dt++)
#pragma unroll
      for (int r = 0; r < 4; r++) {
        const float v = o_acc[mt][dt][r] / l_run[mt][r];
        O[(w * 32 + mt * 16 + q4 * 4 + r) * 512 + dt * 16 + l15] = f2b(v);
      }
}

extern "C" void kernel_launch(void* const* d_in, const int* in_sizes, int n_in,
                              void* d_out, int out_size, void* d_ws, size_t ws_size,
                              hipStream_t stream) {
  const float* regions   = (const float*)d_in[0];
  const float* grids     = (const float*)d_in[1];
  const float* interests = (const float*)d_in[2];
  const int*   mask_r    = (const int*)d_in[3];
  const int*   mask_g    = (const int*)d_in[4];
  const float* aw        = (const float*)d_in[5];
  const float* Wq  = (const float*)d_in[6];  const float* bq  = (const float*)d_in[7];
  const float* Wk  = (const float*)d_in[8];  const float* bk  = (const float*)d_in[9];
  const float* Wv  = (const float*)d_in[10]; const float* bv  = (const float*)d_in[11];
  const float* Wq12= (const float*)d_in[12]; const float* bq12= (const float*)d_in[13];
  const float* Wo1 = (const float*)d_in[14]; const float* bo1 = (const float*)d_in[15];
  const float* Wo2 = (const float*)d_in[16]; const float* bo2 = (const float*)d_in[17];
  u16*   ws  = (u16*)d_ws;
  float* out = (float*)d_out;

  gemm_all<<<dim3(4, 32, 6), 256, 0, stream>>>(regions, grids, interests, aw,
      Wq, bq, Wk, bk, Wv, bv, Wq12, bq12, Wo1, bo1, Wo2, bo2, ws, out, 0);
  attn_kernel<<<dim3(16, 16, 2), 256, 0, stream>>>(mask_r, mask_g, ws);
  gemm_all<<<dim3(4, 32, 2), 256, 0, stream>>>(regions, grids, interests, aw,
      Wq, bq, Wk, bk, Wv, bv, Wq12, bq12, Wo1, bo1, Wo2, bo2, ws, out, 1);
}

// Round 5
// 238.794 us; speedup vs baseline: 1.5095x; 1.2392x over previous
//
#include <hip/hip_runtime.h>
#include <hip/hip_bf16.h>

typedef __attribute__((ext_vector_type(8))) __bf16 bf16x8;
typedef __attribute__((ext_vector_type(4))) float f32x4;
typedef __attribute__((ext_vector_type(4))) int   i32x4;
typedef unsigned short u16;

// B=2, N=2048, D_MODEL=512, H=8, DK=DV=64. I/O f32; ws intermediates bf16.
// ws (u16 elems), 10 segs x 2M:
//  0 qA  1 qB  2 k1  3 k2  4 v1^T  5 v2^T
//  6 regions_bf (later O1)  7 grids_bf (later O2)  8 interests_bf
//  9 weights: Wq@0 Wk@262144 Wv@524288 Wq12@786432 Wo1@1048576 Wo2@1310720
#define WS_SEG 2097152

static __device__ __forceinline__ u16 f2b(float f) {
  __hip_bfloat16 h = __float2bfloat16(f);  // RNE
  return __builtin_bit_cast(u16, h);
}
static __device__ __forceinline__ i32x4 cvt8(const float* __restrict__ p) {
  float4 a = *(const float4*)p;
  float4 b = *(const float4*)(p + 4);
  union { i32x4 v; u16 u[8]; } r;
  r.u[0]=f2b(a.x); r.u[1]=f2b(a.y); r.u[2]=f2b(a.z); r.u[3]=f2b(a.w);
  r.u[4]=f2b(b.x); r.u[5]=f2b(b.y); r.u[6]=f2b(b.z); r.u[7]=f2b(b.w);
  return r.v;
}
static __device__ __forceinline__ float fexp2(float x) {
  float r; asm("v_exp_f32 %0, %1" : "=v"(r) : "v"(x)); return r;
}
template<int C>
static __device__ __forceinline__ float dppf(float x) {
  int v = __builtin_amdgcn_update_dpp(__builtin_bit_cast(int, x),
                                      __builtin_bit_cast(int, x), C, 0xF, 0xF, false);
  return __builtin_bit_cast(float, v);
}
static __device__ __forceinline__ float rowsum16(float x) {
  x += dppf<0xB1>(x);    // xor1
  x += dppf<0x4E>(x);    // xor2
  x += dppf<0x141>(x);   // row_half_mirror
  x += dppf<0x140>(x);   // row_mirror
  return x;
}
// async 16B global -> LDS (dest = wave-uniform base + lane*16)
static __device__ __forceinline__ void gld16(const u16* gp, u16* lp) {
  __builtin_amdgcn_global_load_lds(
      (const __attribute__((address_space(1))) void*)gp,
      (__attribute__((address_space(3))) void*)lp, 16, 0, 0);
}

// ---------------------------------------------------------------------------
// Pre-convert f32 -> bf16 into ws (activations + weights)
// ---------------------------------------------------------------------------
__global__ __launch_bounds__(256) void convert_kernel(
    const float* __restrict__ regions, const float* __restrict__ grids,
    const float* __restrict__ interests,
    const float* __restrict__ Wq, const float* __restrict__ Wk,
    const float* __restrict__ Wv, const float* __restrict__ Wq12,
    const float* __restrict__ Wo1, const float* __restrict__ Wo2,
    u16* __restrict__ ws)
{
  const size_t i = (size_t)(blockIdx.x * 256 + threadIdx.x) * 8;
  const float* s; u16* d;
  if (i < 2097152)      { s = regions   + i;           d = ws + 6 * WS_SEG + i; }
  else if (i < 4194304) { s = grids     + (i - 2097152); d = ws + 7 * WS_SEG + (i - 2097152); }
  else if (i < 6291456) { s = interests + (i - 4194304); d = ws + 8 * WS_SEG + (i - 4194304); }
  else {
    const size_t j = i - 6291456;          // 0 .. 1572863
    d = ws + 9 * WS_SEG + j;
    if (j < 262144)       s = Wq  + j;
    else if (j < 524288)  s = Wk  + (j - 262144);
    else if (j < 786432)  s = Wv  + (j - 524288);
    else if (j < 1048576) s = Wq12+ (j - 786432);
    else if (j < 1310720) s = Wo1 + (j - 1048576);
    else                  s = Wo2 + (j - 1310720);
  }
  *(i32x4*)d = cvt8(s);
}

// ---------------------------------------------------------------------------
// bt-GEMM, 128x128 tile, BK=32, 4 waves x 64x64, bf16 sources in ws,
// global_load_lds(16B) staging with XOR-swizzled stride-32 LDS layout.
// phase 0: z0 qA (K=1024 concat), z1 qB, z2 k1 (*scale*log2e*aw), z3 k2,
//          z4 v1^T (swapped operands), z5 v2^T
// phase 1: z0/z1 out = O_z @ Wo_z^T + bo_z -> f32 d_out
// ---------------------------------------------------------------------------
__global__ __launch_bounds__(256, 2) void gemm_all(
    const float* __restrict__ aw,
    const float* __restrict__ bq,  const float* __restrict__ bk,
    const float* __restrict__ bv,  const float* __restrict__ bq12,
    const float* __restrict__ bo1, const float* __restrict__ bo2,
    u16* __restrict__ ws, float* __restrict__ out, int phase)
{
  __shared__ u16 As[128 * 32];   // stride 32, XOR-swizzled chunks
  __shared__ u16 Bs[128 * 32];

  const u16* regs_bf = ws + 6 * WS_SEG;
  const u16* grid_bf = ws + 7 * WS_SEG;
  const u16* intr_bf = ws + 8 * WS_SEG;
  const u16* Wt      = ws + 9 * WS_SEG;
  const u16* Wq_bf   = Wt;
  const u16* Wk_bf   = Wt + 262144;
  const u16* Wv_bf   = Wt + 524288;
  const u16* Wq12_bf = Wt + 786432;
  const u16* Wo1_bf  = Wt + 1048576;
  const u16* Wo2_bf  = Wt + 1310720;

  const u16 *A1 = nullptr, *A2 = nullptr, *B1 = nullptr, *B2 = nullptr;
  const float *bias1 = nullptr, *bias2 = nullptr;
  u16* dst16 = nullptr;
  float* dst32 = nullptr;
  int KT = 512, epi = 0;
  const int z = blockIdx.z;
  if (phase == 0) {
    if (z == 0)      { A1=intr_bf; A2=grid_bf; B1=Wq_bf; B2=Wq12_bf; KT=1024; bias1=bq; bias2=bq12; epi=0; dst16=ws+0*WS_SEG; }
    else if (z == 1) { A1=intr_bf; A2=regs_bf; B1=Wq_bf; B2=Wq12_bf; KT=1024; bias1=bq; bias2=bq12; epi=0; dst16=ws+1*WS_SEG; }
    else if (z == 2) { A1=regs_bf; B1=Wk_bf; bias1=bk; epi=1; dst16=ws+2*WS_SEG; }
    else if (z == 3) { A1=grid_bf; B1=Wk_bf; bias1=bk; epi=1; dst16=ws+3*WS_SEG; }
    else if (z == 4) { A1=regs_bf; B1=Wv_bf; bias1=bv; epi=3; dst16=ws+4*WS_SEG; }
    else             { A1=grid_bf; B1=Wv_bf; bias1=bv; epi=3; dst16=ws+5*WS_SEG; }
  } else {
    if (z == 0) { A1=ws+6*WS_SEG; B1=Wo1_bf; bias1=bo1; epi=2; dst32=out; }
    else        { A1=ws+7*WS_SEG; B1=Wo2_bf; bias1=bo2; epi=2; dst32=out + 2097152; }
  }
  const bool swp = (epi == 3);

  const int t = threadIdx.x;
  const int lane = t & 63, w = t >> 6;
  const int l15 = lane & 15, q4 = lane >> 4;
  const int m0 = blockIdx.y * 128, j0 = blockIdx.x * 128;
  const int ro = (w >> 1) * 64, co = (w & 1) * 64;

  f32x4 acc[4][4];
  for (int i = 0; i < 4; i++)
    for (int j = 0; j < 4; j++) acc[i][j] = (f32x4){0.f, 0.f, 0.f, 0.f};

  for (int k0 = 0; k0 < KT; k0 += 32) {
    const u16* pa; const u16* pb; int kk = k0, ra, rb;
    if (swp)           { pa = B1; pb = A1; ra = j0; rb = m0; }
    else if (kk < 512) { pa = A1; pb = B1; ra = m0; rb = j0; }
    else               { pa = A2; pb = B2; ra = m0; rb = j0; kk -= 512; }
    __syncthreads();
#pragma unroll
    for (int c = 0; c < 2; c++) {
      const int cidx = w * 2 + c;                       // 16-row group
      const int R = cidx * 16 + (lane >> 2);            // LDS row this lane fills
      const int cg = (lane & 3) ^ ((R >> 2) & 3);       // content chunk (swizzle)
      gld16(&pa[(ra + R) * 512 + kk + cg * 8], &As[cidx * 512]);
      gld16(&pb[(rb + R) * 512 + kk + cg * 8], &Bs[cidx * 512]);
    }
    __syncthreads();
    bf16x8 af[4], bfr[4];
#pragma unroll
    for (int i = 0; i < 4; i++) {
      const int r = ro + i * 16 + l15;
      af[i] = *(const bf16x8*)&As[r * 32 + (q4 ^ ((r >> 2) & 3)) * 8];
    }
#pragma unroll
    for (int i = 0; i < 4; i++) {
      const int r = co + i * 16 + l15;
      bfr[i] = *(const bf16x8*)&Bs[r * 32 + (q4 ^ ((r >> 2) & 3)) * 8];
    }
#pragma unroll
    for (int mt = 0; mt < 4; mt++)
#pragma unroll
      for (int nt = 0; nt < 4; nt++)
        acc[mt][nt] = __builtin_amdgcn_mfma_f32_16x16x32_bf16(af[mt], bfr[nt], acc[mt][nt], 0, 0, 0);
  }

#pragma unroll
  for (int nt = 0; nt < 4; nt++) {
    if (epi == 3) {
      // swapped: C row = hd, col = token; write V^T = [b*512+hd][token]
      const int token = m0 + co + nt * 16 + l15;
      const int bb = token >> 11, nn = token & 2047;
#pragma unroll
      for (int mt = 0; mt < 4; mt++)
#pragma unroll
        for (int r = 0; r < 4; r++) {
          const int hd = j0 + ro + mt * 16 + q4 * 4 + r;
          dst16[(bb * 512 + hd) * 2048 + nn] = f2b(acc[mt][nt][r] + bias1[hd]);
        }
    } else {
      const int j = j0 + co + nt * 16 + l15;
      float bsum = bias1[j];
      if (bias2) bsum += bias2[j];
#pragma unroll
      for (int mt = 0; mt < 4; mt++)
#pragma unroll
        for (int r = 0; r < 4; r++) {
          const int m = m0 + ro + mt * 16 + q4 * 4 + r;
          float v = acc[mt][nt][r] + bsum;
          if (epi == 2) {
            dst32[m * 512 + j] = v;
          } else {
            const int b = m >> 11, nn = m & 2047, h = j >> 6, d = j & 63;
            if (epi == 1) v *= 0.18033688f * aw[b * 2048 + nn];  // scale*log2e*aw
            dst16[((b * 8 + h) * 2048 + nn) * 64 + d] = f2b(v);
          }
        }
    }
  }
}

// ---------------------------------------------------------------------------
// Flash attention, fixed-max streaming softmax (exp2 domain, M=16 folded into
// mask bias). Block = 128 q-rows of one (path,b,h); wave = 32 rows.
// ---------------------------------------------------------------------------
__global__ __launch_bounds__(256, 2) void attn_kernel(
    const int* __restrict__ mask_r, const int* __restrict__ mask_g,
    u16* __restrict__ ws)
{
  const int qt = blockIdx.x, bh = blockIdx.y, path = blockIdx.z;
  const int b = bh >> 3, h = bh & 7;
  const u16* Q  = (path ? ws + 1 * WS_SEG : ws + 0 * WS_SEG) + bh * (2048 * 64);
  const u16* K  = (path ? ws + 3 * WS_SEG : ws + 2 * WS_SEG) + bh * (2048 * 64);
  const u16* Vg = (path ? ws + 5 * WS_SEG : ws + 4 * WS_SEG) + (b * 512 + h * 64) * 2048;
  const int* mask = (path ? mask_g : mask_r) + b * 2048;
  u16* O = (path ? ws + 7 * WS_SEG : ws + 6 * WS_SEG) + (b * 2048 + qt * 128) * 512 + h * 64;

  __shared__ u16 Ks[64 * 72];     // [key][d]
  __shared__ u16 Vs[64 * 72];     // [d][key] (V^T in ws)
  __shared__ u16 Ps[128 * 64];    // XOR-swizzled P round-trip
  __shared__ float Ms[2048];      // mask bias - 16 (fixed max)

  const int t = threadIdx.x, lane = t & 63, w = t >> 6;
  const int l15 = lane & 15, q4 = lane >> 4;

  {
    const int4 a = *(const int4*)&mask[t * 8];
    const int4 c = *(const int4*)&mask[t * 8 + 4];
    float4 f1, f2v;
    f1.x = (a.x ? -1e30f : 0.f) - 16.f; f1.y = (a.y ? -1e30f : 0.f) - 16.f;
    f1.z = (a.z ? -1e30f : 0.f) - 16.f; f1.w = (a.w ? -1e30f : 0.f) - 16.f;
    f2v.x = (c.x ? -1e30f : 0.f) - 16.f; f2v.y = (c.y ? -1e30f : 0.f) - 16.f;
    f2v.z = (c.z ? -1e30f : 0.f) - 16.f; f2v.w = (c.w ? -1e30f : 0.f) - 16.f;
    *(float4*)&Ms[t * 8] = f1;
    *(float4*)&Ms[t * 8 + 4] = f2v;
  }

  bf16x8 qf[2][2];
#pragma unroll
  for (int mt = 0; mt < 2; mt++) {
    const int qrow = qt * 128 + w * 32 + mt * 16 + l15;
    qf[mt][0] = *(const bf16x8*)&Q[qrow * 64 + q4 * 8];
    qf[mt][1] = *(const bf16x8*)&Q[qrow * 64 + 32 + q4 * 8];
  }

  float l_run[2][4];
  f32x4 o_acc[2][4];
#pragma unroll
  for (int mt = 0; mt < 2; mt++) {
#pragma unroll
    for (int r = 0; r < 4; r++) l_run[mt][r] = 0.f;
#pragma unroll
    for (int d = 0; d < 4; d++) o_acc[mt][d] = (f32x4){0.f, 0.f, 0.f, 0.f};
  }

  for (int kt = 0; kt < 32; kt++) {
    __syncthreads();
#pragma unroll
    for (int seg = 0; seg < 2; seg++) {
      const int c = t + seg * 256;
      const int row = c >> 3, col = (c & 7) * 8;
      *(i32x4*)&Ks[row * 72 + col] = *(const i32x4*)&K[(kt * 64 + row) * 64 + col];
      *(i32x4*)&Vs[row * 72 + col] = *(const i32x4*)&Vg[row * 2048 + kt * 64 + col];
    }
    __syncthreads();

    // S = Q K^T (scale*log2e*aw pre-folded into K)
    f32x4 s[2][4];
#pragma unroll
    for (int mt = 0; mt < 2; mt++)
#pragma unroll
      for (int nt = 0; nt < 4; nt++) s[mt][nt] = (f32x4){0.f, 0.f, 0.f, 0.f};
#pragma unroll
    for (int nt = 0; nt < 4; nt++)
#pragma unroll
      for (int ss = 0; ss < 2; ss++) {
        bf16x8 kf = *(const bf16x8*)&Ks[(nt * 16 + l15) * 72 + ss * 32 + q4 * 8];
        s[0][nt] = __builtin_amdgcn_mfma_f32_16x16x32_bf16(qf[0][ss], kf, s[0][nt], 0, 0, 0);
        s[1][nt] = __builtin_amdgcn_mfma_f32_16x16x32_bf16(qf[1][ss], kf, s[1][nt], 0, 0, 0);
      }

    // p = exp2(s + maskbias - 16); accumulate per-lane l; no max tracking
#pragma unroll
    for (int nt = 0; nt < 4; nt++) {
      const float bias = Ms[kt * 64 + nt * 16 + l15];
#pragma unroll
      for (int mt = 0; mt < 2; mt++)
#pragma unroll
        for (int r = 0; r < 4; r++) {
          const float p = fexp2(s[mt][nt][r] + bias);
          s[mt][nt][r] = p;
          l_run[mt][r] += p;
        }
    }

    // P: C-layout -> A-layout via XOR-swizzled per-wave LDS round trip
#pragma unroll
    for (int mt = 0; mt < 2; mt++)
#pragma unroll
      for (int nt = 0; nt < 4; nt++) {
        const int cg = 2 * nt + (l15 >> 3);
#pragma unroll
        for (int r = 0; r < 4; r++) {
          const int row = w * 32 + mt * 16 + q4 * 4 + r;
          Ps[row * 64 + ((cg ^ (row & 7)) * 8) + (l15 & 7)] = f2b(s[mt][nt][r]);
        }
      }
    asm volatile("s_waitcnt lgkmcnt(0)" ::: "memory");  // wave-local RAW on Ps

    // O += P V
#pragma unroll
    for (int ss = 0; ss < 2; ss++) {
      bf16x8 pf[2];
#pragma unroll
      for (int mt = 0; mt < 2; mt++) {
        const int row = w * 32 + mt * 16 + l15;
        const int cg = (4 * ss + q4) ^ (row & 7);
        pf[mt] = *(const bf16x8*)&Ps[row * 64 + cg * 8];
      }
#pragma unroll
      for (int dt = 0; dt < 4; dt++) {
        bf16x8 vf = *(const bf16x8*)&Vs[(dt * 16 + l15) * 72 + ss * 32 + q4 * 8];
        o_acc[0][dt] = __builtin_amdgcn_mfma_f32_16x16x32_bf16(pf[0], vf, o_acc[0][dt], 0, 0, 0);
        o_acc[1][dt] = __builtin_amdgcn_mfma_f32_16x16x32_bf16(pf[1], vf, o_acc[1][dt], 0, 0, 0);
      }
    }
  }

#pragma unroll
  for (int mt = 0; mt < 2; mt++)
#pragma unroll
    for (int r = 0; r < 4; r++) {
      const float inv = 1.f / rowsum16(l_run[mt][r]);
#pragma unroll
      for (int dt = 0; dt < 4; dt++) {
        O[(w * 32 + mt * 16 + q4 * 4 + r) * 512 + dt * 16 + l15] = f2b(o_acc[mt][dt][r] * inv);
      }
    }
}

extern "C" void kernel_launch(void* const* d_in, const int* in_sizes, int n_in,
                              void* d_out, int out_size, void* d_ws, size_t ws_size,
                              hipStream_t stream) {
  const float* regions   = (const float*)d_in[0];
  const float* grids     = (const float*)d_in[1];
  const float* interests = (const float*)d_in[2];
  const int*   mask_r    = (const int*)d_in[3];
  const int*   mask_g    = (const int*)d_in[4];
  const float* aw        = (const float*)d_in[5];
  const float* Wq  = (const float*)d_in[6];  const float* bq  = (const float*)d_in[7];
  const float* Wk  = (const float*)d_in[8];  const float* bk  = (const float*)d_in[9];
  const float* Wv  = (const float*)d_in[10]; const float* bv  = (const float*)d_in[11];
  const float* Wq12= (const float*)d_in[12]; const float* bq12= (const float*)d_in[13];
  const float* Wo1 = (const float*)d_in[14]; const float* bo1 = (const float*)d_in[15];
  const float* Wo2 = (const float*)d_in[16]; const float* bo2 = (const float*)d_in[17];
  u16*   ws  = (u16*)d_ws;
  float* out = (float*)d_out;

  // 0) f32 -> bf16 pre-convert (activations + weights)
  convert_kernel<<<3840, 256, 0, stream>>>(regions, grids, interests,
      Wq, Wk, Wv, Wq12, Wo1, Wo2, ws);
  // 1) projections
  gemm_all<<<dim3(4, 32, 6), 256, 0, stream>>>(aw, bq, bk, bv, bq12, bo1, bo2,
      ws, out, 0);
  // 2) flash attention
  attn_kernel<<<dim3(16, 16, 2), 256, 0, stream>>>(mask_r, mask_g, ws);
  // 3) output projections -> d_out (f32)
  gemm_all<<<dim3(4, 32, 2), 256, 0, stream>>>(aw, bq, bk, bv, bq12, bo1, bo2,
      ws, out, 1);
}

// Round 6
// 202.389 us; speedup vs baseline: 1.7810x; 1.1799x over previous
//
#include <hip/hip_runtime.h>
#include <hip/hip_bf16.h>

typedef __attribute__((ext_vector_type(8))) __bf16 bf16x8;
typedef __attribute__((ext_vector_type(4))) float f32x4;
typedef __attribute__((ext_vector_type(4))) int   i32x4;
typedef unsigned short u16;

// B=2, N=2048, D_MODEL=512, H=8, DK=DV=64. I/O f32; ws intermediates bf16.
// ws (u16 elems), 10 segs x 2M:
//  0 qA  1 qB  2 k1  3 k2  4 v1^T  5 v2^T
//  6 regions_bf (later O1)  7 grids_bf (later O2)  8 interests_bf
//  9 weights: Wq@0 Wk@262144 Wv@524288 Wq12@786432 Wo1@1048576 Wo2@1310720
#define WS_SEG 2097152

static __device__ __forceinline__ u16 f2b(float f) {
  __hip_bfloat16 h = __float2bfloat16(f);  // RNE
  return __builtin_bit_cast(u16, h);
}
static __device__ __forceinline__ i32x4 cvt8(const float* __restrict__ p) {
  float4 a = *(const float4*)p;
  float4 b = *(const float4*)(p + 4);
  union { i32x4 v; u16 u[8]; } r;
  r.u[0]=f2b(a.x); r.u[1]=f2b(a.y); r.u[2]=f2b(a.z); r.u[3]=f2b(a.w);
  r.u[4]=f2b(b.x); r.u[5]=f2b(b.y); r.u[6]=f2b(b.z); r.u[7]=f2b(b.w);
  return r.v;
}
static __device__ __forceinline__ float fexp2(float x) {
  float r; asm("v_exp_f32 %0, %1" : "=v"(r) : "v"(x)); return r;
}
template<int C>
static __device__ __forceinline__ float dppf(float x) {
  int v = __builtin_amdgcn_update_dpp(__builtin_bit_cast(int, x),
                                      __builtin_bit_cast(int, x), C, 0xF, 0xF, false);
  return __builtin_bit_cast(float, v);
}
static __device__ __forceinline__ float rowsum16(float x) {
  x += dppf<0xB1>(x);    // xor1
  x += dppf<0x4E>(x);    // xor2
  x += dppf<0x141>(x);   // row_half_mirror
  x += dppf<0x140>(x);   // row_mirror
  return x;
}
// async 16B global -> LDS (dest = wave-uniform base + lane*16)
static __device__ __forceinline__ void gld16(const u16* gp, u16* lp) {
  __builtin_amdgcn_global_load_lds(
      (const __attribute__((address_space(1))) void*)gp,
      (__attribute__((address_space(3))) void*)lp, 16, 0, 0);
}

// ---------------------------------------------------------------------------
// Pre-convert f32 -> bf16 into ws (activations + weights)
// ---------------------------------------------------------------------------
__global__ __launch_bounds__(256) void convert_kernel(
    const float* __restrict__ regions, const float* __restrict__ grids,
    const float* __restrict__ interests,
    const float* __restrict__ Wq, const float* __restrict__ Wk,
    const float* __restrict__ Wv, const float* __restrict__ Wq12,
    const float* __restrict__ Wo1, const float* __restrict__ Wo2,
    u16* __restrict__ ws)
{
  const size_t i = (size_t)(blockIdx.x * 256 + threadIdx.x) * 8;
  const float* s; u16* d;
  if (i < 2097152)      { s = regions   + i;           d = ws + 6 * WS_SEG + i; }
  else if (i < 4194304) { s = grids     + (i - 2097152); d = ws + 7 * WS_SEG + (i - 2097152); }
  else if (i < 6291456) { s = interests + (i - 4194304); d = ws + 8 * WS_SEG + (i - 4194304); }
  else {
    const size_t j = i - 6291456;          // 0 .. 1572863
    d = ws + 9 * WS_SEG + j;
    if (j < 262144)       s = Wq  + j;
    else if (j < 524288)  s = Wk  + (j - 262144);
    else if (j < 786432)  s = Wv  + (j - 524288);
    else if (j < 1048576) s = Wq12+ (j - 786432);
    else if (j < 1310720) s = Wo1 + (j - 1048576);
    else                  s = Wo2 + (j - 1310720);
  }
  *(i32x4*)d = cvt8(s);
}

// ---------------------------------------------------------------------------
// bt-GEMM, MTx128 tile, BK=64, 4 waves. global_load_lds staging, XOR-swizzled
// stride-64 LDS rows (8 chunks of 16B; content c stored at slot c^(row&7)).
// phase 0 (MT=128): z0 qA (K=1024 concat), z1 qB, z2 k1 (*scale*log2e*aw),
//                   z3 k2, z4 v1^T (swapped operands), z5 v2^T
// phase 1 (MT=64):  z0/z1 out = O_z @ Wo_z^T + bo_z -> f32 d_out
// ---------------------------------------------------------------------------
template<int MT>
__global__ __launch_bounds__(256, 2) void gemm_all(
    const float* __restrict__ aw,
    const float* __restrict__ bq,  const float* __restrict__ bk,
    const float* __restrict__ bv,  const float* __restrict__ bq12,
    const float* __restrict__ bo1, const float* __restrict__ bo2,
    u16* __restrict__ ws, float* __restrict__ out, int phase)
{
  __shared__ u16 As[MT * 64];
  __shared__ u16 Bs[128 * 64];
  constexpr int MFR = MT / 32;       // m-frags per wave

  const u16* regs_bf = ws + 6 * WS_SEG;
  const u16* grid_bf = ws + 7 * WS_SEG;
  const u16* intr_bf = ws + 8 * WS_SEG;
  const u16* Wt      = ws + 9 * WS_SEG;

  const u16 *A1 = nullptr, *A2 = nullptr, *B1 = nullptr, *B2 = nullptr;
  const float *bias1 = nullptr, *bias2 = nullptr;
  u16* dst16 = nullptr;
  float* dst32 = nullptr;
  int KT = 512, epi = 0;
  const int z = blockIdx.z;
  if (phase == 0) {
    if (z == 0)      { A1=intr_bf; A2=grid_bf; B1=Wt; B2=Wt+786432; KT=1024; bias1=bq; bias2=bq12; epi=0; dst16=ws+0*WS_SEG; }
    else if (z == 1) { A1=intr_bf; A2=regs_bf; B1=Wt; B2=Wt+786432; KT=1024; bias1=bq; bias2=bq12; epi=0; dst16=ws+1*WS_SEG; }
    else if (z == 2) { A1=regs_bf; B1=Wt+262144; bias1=bk; epi=1; dst16=ws+2*WS_SEG; }
    else if (z == 3) { A1=grid_bf; B1=Wt+262144; bias1=bk; epi=1; dst16=ws+3*WS_SEG; }
    else if (z == 4) { A1=regs_bf; B1=Wt+524288; bias1=bv; epi=3; dst16=ws+4*WS_SEG; }
    else             { A1=grid_bf; B1=Wt+524288; bias1=bv; epi=3; dst16=ws+5*WS_SEG; }
  } else {
    if (z == 0) { A1=ws+6*WS_SEG; B1=Wt+1048576; bias1=bo1; epi=2; dst32=out; }
    else        { A1=ws+7*WS_SEG; B1=Wt+1310720; bias1=bo2; epi=2; dst32=out + 2097152; }
  }
  const bool swp = (epi == 3);

  const int t = threadIdx.x;
  const int lane = t & 63, w = t >> 6;
  const int l15 = lane & 15, q4 = lane >> 4;
  const int m0 = blockIdx.y * MT, j0 = blockIdx.x * 128;
  const int ro = (w >> 1) * (MT / 2), co = (w & 1) * 64;

  f32x4 acc[MFR][4];
  for (int i = 0; i < MFR; i++)
    for (int j = 0; j < 4; j++) acc[i][j] = (f32x4){0.f, 0.f, 0.f, 0.f};

  for (int k0 = 0; k0 < KT; k0 += 64) {
    const u16* pa; const u16* pb; int kk = k0, ra, rb;
    if (swp)           { pa = B1; pb = A1; ra = j0; rb = m0; }
    else if (kk < 512) { pa = A1; pb = B1; ra = m0; rb = j0; }
    else               { pa = A2; pb = B2; ra = m0; rb = j0; kk -= 512; }
    __syncthreads();
    // stage A: MT rows x 64 elems; each gld16 fills 8 rows (1 KB)
#pragma unroll
    for (int c = 0; c < MFR; c++) {
      const int cidx = w * MFR + c;
      const int row = cidx * 8 + (lane >> 3);
      const int cg = (lane & 7) ^ (row & 7);
      gld16(&pa[(ra + row) * 512 + kk + cg * 8], &As[cidx * 512]);
    }
    // stage B: 128 rows
#pragma unroll
    for (int c = 0; c < 4; c++) {
      const int cidx = w * 4 + c;
      const int row = cidx * 8 + (lane >> 3);
      const int cg = (lane & 7) ^ (row & 7);
      gld16(&pb[(rb + row) * 512 + kk + cg * 8], &Bs[cidx * 512]);
    }
    __syncthreads();
#pragma unroll
    for (int h = 0; h < 2; h++) {
      bf16x8 af[MFR], bfr[4];
#pragma unroll
      for (int i = 0; i < MFR; i++) {
        const int r = ro + i * 16 + l15;
        af[i] = *(const bf16x8*)&As[r * 64 + (((h * 4 + q4) ^ (r & 7)) * 8)];
      }
#pragma unroll
      for (int i = 0; i < 4; i++) {
        const int r = co + i * 16 + l15;
        bfr[i] = *(const bf16x8*)&Bs[r * 64 + (((h * 4 + q4) ^ (r & 7)) * 8)];
      }
#pragma unroll
      for (int mt = 0; mt < MFR; mt++)
#pragma unroll
        for (int nt = 0; nt < 4; nt++)
          acc[mt][nt] = __builtin_amdgcn_mfma_f32_16x16x32_bf16(af[mt], bfr[nt], acc[mt][nt], 0, 0, 0);
    }
  }

#pragma unroll
  for (int nt = 0; nt < 4; nt++) {
    if (epi == 3) {
      // swapped: C row = hd, col = token; write V^T = [b*512+hd][token]
      const int token = m0 + co + nt * 16 + l15;
      const int bb = token >> 11, nn = token & 2047;
#pragma unroll
      for (int mt = 0; mt < MFR; mt++)
#pragma unroll
        for (int r = 0; r < 4; r++) {
          const int hd = j0 + ro + mt * 16 + q4 * 4 + r;
          dst16[(bb * 512 + hd) * 2048 + nn] = f2b(acc[mt][nt][r] + bias1[hd]);
        }
    } else {
      const int j = j0 + co + nt * 16 + l15;
      float bsum = bias1[j];
      if (bias2) bsum += bias2[j];
#pragma unroll
      for (int mt = 0; mt < MFR; mt++)
#pragma unroll
        for (int r = 0; r < 4; r++) {
          const int m = m0 + ro + mt * 16 + q4 * 4 + r;
          float v = acc[mt][nt][r] + bsum;
          if (epi == 2) {
            dst32[m * 512 + j] = v;
          } else {
            const int b = m >> 11, nn = m & 2047, h = j >> 6, d = j & 63;
            if (epi == 1) v *= 0.18033688f * aw[b * 2048 + nn];  // scale*log2e*aw
            dst16[((b * 8 + h) * 2048 + nn) * 64 + d] = f2b(v);
          }
        }
    }
  }
}

// ---------------------------------------------------------------------------
// Flash attention, fixed-max streaming softmax (exp2 domain, M=16 folded into
// mask bias). Block = 128 q-rows of one (path,b,h); wave = 32 rows.
// K/V staged via global_load_lds into XOR-swizzled stride-64 LDS.
// ---------------------------------------------------------------------------
__global__ __launch_bounds__(256, 2) void attn_kernel(
    const int* __restrict__ mask_r, const int* __restrict__ mask_g,
    u16* __restrict__ ws)
{
  const int qt = blockIdx.x, bh = blockIdx.y, path = blockIdx.z;
  const int b = bh >> 3, h = bh & 7;
  const u16* Q  = (path ? ws + 1 * WS_SEG : ws + 0 * WS_SEG) + bh * (2048 * 64);
  const u16* K  = (path ? ws + 3 * WS_SEG : ws + 2 * WS_SEG) + bh * (2048 * 64);
  const u16* Vg = (path ? ws + 5 * WS_SEG : ws + 4 * WS_SEG) + (b * 512 + h * 64) * 2048;
  const int* mask = (path ? mask_g : mask_r) + b * 2048;
  u16* O = (path ? ws + 7 * WS_SEG : ws + 6 * WS_SEG) + (b * 2048 + qt * 128) * 512 + h * 64;

  __shared__ u16 Ks[64 * 64];     // [key][d], swizzled chunks
  __shared__ u16 Vs[64 * 64];     // [d][key], swizzled chunks
  __shared__ u16 Ps[128 * 64];    // XOR-swizzled P round-trip
  __shared__ float Ms[2048];      // mask bias - 16 (fixed max)

  const int t = threadIdx.x, lane = t & 63, w = t >> 6;
  const int l15 = lane & 15, q4 = lane >> 4;

  {
    const int4 a = *(const int4*)&mask[t * 8];
    const int4 c = *(const int4*)&mask[t * 8 + 4];
    float4 f1, f2v;
    f1.x = (a.x ? -1e30f : 0.f) - 16.f; f1.y = (a.y ? -1e30f : 0.f) - 16.f;
    f1.z = (a.z ? -1e30f : 0.f) - 16.f; f1.w = (a.w ? -1e30f : 0.f) - 16.f;
    f2v.x = (c.x ? -1e30f : 0.f) - 16.f; f2v.y = (c.y ? -1e30f : 0.f) - 16.f;
    f2v.z = (c.z ? -1e30f : 0.f) - 16.f; f2v.w = (c.w ? -1e30f : 0.f) - 16.f;
    *(float4*)&Ms[t * 8] = f1;
    *(float4*)&Ms[t * 8 + 4] = f2v;
  }

  bf16x8 qf[2][2];
#pragma unroll
  for (int mt = 0; mt < 2; mt++) {
    const int qrow = qt * 128 + w * 32 + mt * 16 + l15;
    qf[mt][0] = *(const bf16x8*)&Q[qrow * 64 + q4 * 8];
    qf[mt][1] = *(const bf16x8*)&Q[qrow * 64 + 32 + q4 * 8];
  }

  float l_run[2][4];
  f32x4 o_acc[2][4];
#pragma unroll
  for (int mt = 0; mt < 2; mt++) {
#pragma unroll
    for (int r = 0; r < 4; r++) l_run[mt][r] = 0.f;
#pragma unroll
    for (int d = 0; d < 4; d++) o_acc[mt][d] = (f32x4){0.f, 0.f, 0.f, 0.f};
  }

  for (int kt = 0; kt < 32; kt++) {
    __syncthreads();
#pragma unroll
    for (int c = 0; c < 2; c++) {           // async stage K and V^T (8 KB each)
      const int cidx = w * 2 + c;
      const int row = cidx * 8 + (lane >> 3);
      const int cg = (lane & 7) ^ (row & 7);
      gld16(&K[(kt * 64 + row) * 64 + cg * 8], &Ks[cidx * 512]);
      gld16(&Vg[row * 2048 + kt * 64 + cg * 8], &Vs[cidx * 512]);
    }
    __syncthreads();

    // S = Q K^T (scale*log2e*aw pre-folded into K)
    f32x4 s[2][4];
#pragma unroll
    for (int mt = 0; mt < 2; mt++)
#pragma unroll
      for (int nt = 0; nt < 4; nt++) s[mt][nt] = (f32x4){0.f, 0.f, 0.f, 0.f};
#pragma unroll
    for (int nt = 0; nt < 4; nt++)
#pragma unroll
      for (int ss = 0; ss < 2; ss++) {
        const int r = nt * 16 + l15;
        bf16x8 kf = *(const bf16x8*)&Ks[r * 64 + (((ss * 4 + q4) ^ (r & 7)) * 8)];
        s[0][nt] = __builtin_amdgcn_mfma_f32_16x16x32_bf16(qf[0][ss], kf, s[0][nt], 0, 0, 0);
        s[1][nt] = __builtin_amdgcn_mfma_f32_16x16x32_bf16(qf[1][ss], kf, s[1][nt], 0, 0, 0);
      }

    // p = exp2(s + maskbias - 16); accumulate per-lane l; no max tracking
#pragma unroll
    for (int nt = 0; nt < 4; nt++) {
      const float bias = Ms[kt * 64 + nt * 16 + l15];
#pragma unroll
      for (int mt = 0; mt < 2; mt++)
#pragma unroll
        for (int r = 0; r < 4; r++) {
          const float p = fexp2(s[mt][nt][r] + bias);
          s[mt][nt][r] = p;
          l_run[mt][r] += p;
        }
    }

    // P: C-layout -> A-layout via XOR-swizzled per-wave LDS round trip
#pragma unroll
    for (int mt = 0; mt < 2; mt++)
#pragma unroll
      for (int nt = 0; nt < 4; nt++) {
        const int cg = 2 * nt + (l15 >> 3);
#pragma unroll
        for (int r = 0; r < 4; r++) {
          const int row = w * 32 + mt * 16 + q4 * 4 + r;
          Ps[row * 64 + ((cg ^ (row & 7)) * 8) + (l15 & 7)] = f2b(s[mt][nt][r]);
        }
      }
    asm volatile("s_waitcnt lgkmcnt(0)" ::: "memory");  // wave-local RAW on Ps

    // O += P V
#pragma unroll
    for (int ss = 0; ss < 2; ss++) {
      bf16x8 pf[2];
#pragma unroll
      for (int mt = 0; mt < 2; mt++) {
        const int row = w * 32 + mt * 16 + l15;
        const int cg = (4 * ss + q4) ^ (row & 7);
        pf[mt] = *(const bf16x8*)&Ps[row * 64 + cg * 8];
      }
#pragma unroll
      for (int dt = 0; dt < 4; dt++) {
        const int r = dt * 16 + l15;
        bf16x8 vf = *(const bf16x8*)&Vs[r * 64 + (((ss * 4 + q4) ^ (r & 7)) * 8)];
        o_acc[0][dt] = __builtin_amdgcn_mfma_f32_16x16x32_bf16(pf[0], vf, o_acc[0][dt], 0, 0, 0);
        o_acc[1][dt] = __builtin_amdgcn_mfma_f32_16x16x32_bf16(pf[1], vf, o_acc[1][dt], 0, 0, 0);
      }
    }
  }

#pragma unroll
  for (int mt = 0; mt < 2; mt++)
#pragma unroll
    for (int r = 0; r < 4; r++) {
      const float inv = 1.f / rowsum16(l_run[mt][r]);
#pragma unroll
      for (int dt = 0; dt < 4; dt++) {
        O[(w * 32 + mt * 16 + q4 * 4 + r) * 512 + dt * 16 + l15] = f2b(o_acc[mt][dt][r] * inv);
      }
    }
}

extern "C" void kernel_launch(void* const* d_in, const int* in_sizes, int n_in,
                              void* d_out, int out_size, void* d_ws, size_t ws_size,
                              hipStream_t stream) {
  const float* regions   = (const float*)d_in[0];
  const float* grids     = (const float*)d_in[1];
  const float* interests = (const float*)d_in[2];
  const int*   mask_r    = (const int*)d_in[3];
  const int*   mask_g    = (const int*)d_in[4];
  const float* aw        = (const float*)d_in[5];
  const float* Wq  = (const float*)d_in[6];  const float* bq  = (const float*)d_in[7];
  const float* Wk  = (const float*)d_in[8];  const float* bk  = (const float*)d_in[9];
  const float* Wv  = (const float*)d_in[10]; const float* bv  = (const float*)d_in[11];
  const float* Wq12= (const float*)d_in[12]; const float* bq12= (const float*)d_in[13];
  const float* Wo1 = (const float*)d_in[14]; const float* bo1 = (const float*)d_in[15];
  const float* Wo2 = (const float*)d_in[16]; const float* bo2 = (const float*)d_in[17];
  u16*   ws  = (u16*)d_ws;
  float* out = (float*)d_out;

  // 0) f32 -> bf16 pre-convert (activations + weights)
  convert_kernel<<<3840, 256, 0, stream>>>(regions, grids, interests,
      Wq, Wk, Wv, Wq12, Wo1, Wo2, ws);
  // 1) projections (128x128 tiles, BK=64)
  gemm_all<128><<<dim3(4, 32, 6), 256, 0, stream>>>(aw, bq, bk, bv, bq12, bo1, bo2,
      ws, out, 0);
  // 2) flash attention
  attn_kernel<<<dim3(16, 16, 2), 256, 0, stream>>>(mask_r, mask_g, ws);
  // 3) output projections (64x128 tiles -> 2 blocks/CU) -> d_out (f32)
  gemm_all<64><<<dim3(4, 64, 2), 256, 0, stream>>>(aw, bq, bk, bv, bq12, bo1, bo2,
      ws, out, 1);
}